// Round 4
// baseline (10632.491 us; speedup 1.0000x reference)
//
#include <hip/hip_runtime.h>
#include <hip/hip_bf16.h>

#define NSEQ 512
#define SEGS 511     // L-1
#define CIN  32

typedef float v2f __attribute__((ext_vector_type(2)));

__device__ __forceinline__ float rl(float v, int lane) {
    return __int_as_float(__builtin_amdgcn_readlane(__float_as_int(v), lane));
}

__device__ __forceinline__ float tanhf_fast(float x) {
    // tanh(x) = sign(x) * (1 - e) / (1 + e),  e = exp(-2|x|)  — no overflow path
    float ax = fabsf(x);
    float e = __expf(-2.0f * ax);
#if __has_builtin(__builtin_amdgcn_rcpf)
    float r = (1.0f - e) * __builtin_amdgcn_rcpf(1.0f + e);
#else
    float r = (1.0f - e) / (1.0f + e);
#endif
    return copysignf(r, x);
}

// One RK4(3/8) vector-field eval for the whole wave.
// lane m holds z_m; lane m holds h-pair (h_{2m}, h_{2m+1}) after mm1.
// mm1: u broadcast via readlane (SGPR), v2f accumulate -> compiler emits
// v_fmac_f32 with SGPR src (legal VOP2) or its own pk_fma setup.
// mm2: h broadcast via readlane, two split scalar chains.
#define MM_STAGE(YS, XC, KOUT) do {                                    \
    v2f he = {0.f, 0.f}, ho = {0.f, 0.f};                              \
    _Pragma("unroll")                                                  \
    for (int i = 0; i < 64; i += 2) {                                  \
        float ue = rl((YS), i), uo = rl((YS), i + 1);                  \
        he += w1p[i] * ue;                                             \
        ho += w1p[i + 1] * uo;                                         \
    }                                                                  \
    _Pragma("unroll")                                                  \
    for (int i = 0; i < 32; i += 2) {                                  \
        float ue = rl((XC), i), uo = rl((XC), i + 1);                  \
        he += w1p[64 + i] * ue;                                        \
        ho += w1p[64 + i + 1] * uo;                                    \
    }                                                                  \
    v2f hs = he + ho + b1p;                                            \
    float h_lo = tanhf_fast(hs.x), h_hi = tanhf_fast(hs.y);            \
    float ze = 0.f, zo = 0.f;                                          \
    _Pragma("unroll")                                                  \
    for (int jj = 0; jj < 64; ++jj) {                                  \
        ze = fmaf(rl(h_lo, jj), w2c[2 * jj], ze);                      \
        zo = fmaf(rl(h_hi, jj), w2c[2 * jj + 1], zo);                  \
    }                                                                  \
    KOUT = tanhf_fast(ze + zo + b2m);                                  \
} while (0)

__global__ __launch_bounds__(64, 1) void node_kernel(
    const float* __restrict__ cA, const float* __restrict__ cB,
    const float* __restrict__ cC, const float* __restrict__ cD,
    const int*   __restrict__ final_index,
    const float* __restrict__ W_init, const float* __restrict__ b_init,
    const float* __restrict__ W1, const float* __restrict__ b1,
    const float* __restrict__ W2, const float* __restrict__ b2,
    const float* __restrict__ W_out, const float* __restrict__ b_out,
    float* __restrict__ out)
{
    const int b    = blockIdx.x;
    const int lane = threadIdx.x;   // 0..63, one wave per block
    const int ch   = lane & 31;

    const float* a_ptr = cA + (size_t)b * SEGS * CIN;
    const float* bp    = cB + (size_t)b * SEGS * CIN;
    const float* cp    = cC + (size_t)b * SEGS * CIN;
    const float* dp    = cD + (size_t)b * SEGS * CIN;

    // ---- weights into registers ----
    // w1p[i] = (W1[i][2*lane], W1[i][2*lane+1]); rows 0..63 = z, 64..95 = X
    v2f w1p[96];
#pragma unroll
    for (int i = 0; i < 96; ++i)
        w1p[i] = *reinterpret_cast<const v2f*>(&W1[i * 128 + 2 * lane]);
    // w2c[2*j+p] = W2[..][lane] column; w2c[2*jj]=W2[2*jj? ] see mm2 indexing:
    // mm2 uses h_{2jj} * w2c[2jj] with w2c[j] = W2[j][lane]
    float w2c[128];
#pragma unroll
    for (int j = 0; j < 128; ++j) w2c[j] = W2[j * 64 + lane];
    v2f   b1p = *reinterpret_cast<const v2f*>(&b1[2 * lane]);
    float b2m = b2[lane];

    // keep-alive pins: force materialization in arch VGPRs before the loop
#pragma unroll
    for (int i = 0; i < 96; ++i) asm volatile("" : "+v"(w1p[i]));
#pragma unroll
    for (int j = 0; j < 128; ++j) asm volatile("" : "+v"(w2c[j]));
    asm volatile("" : "+v"(b1p));
    asm volatile("" : "+v"(b2m));

    // ---- z0 = X(0) @ W_init + b_init ----
    float z = b_init[lane];
    {
        float a0 = a_ptr[ch];
#pragma unroll
        for (int i = 0; i < 32; ++i)
            z = fmaf(rl(a0, i), W_init[i * 64 + lane], z);
    }

    const int fi = final_index[b];

    // current-segment coeffs (lanes 0..31 meaningful, 32..63 duplicate)
    float acur = a_ptr[ch], bcur = bp[ch], ccur = cp[ch], dcur = dp[ch];
    float k1 = 0.f, k2 = 0.f, k3 = 0.f, k4 = 0.f;

    for (int t = 0; t < fi; ++t) {
        // spline points for this step, from CURRENT coeffs only
        float x0  = acur;
        float i13 = fmaf(dcur, 1.0f / 9.0f, 0.5f * ccur);
        float x13 = fmaf(fmaf(i13, 1.0f / 3.0f, bcur), 1.0f / 3.0f, acur);
        float i23 = fmaf(dcur, 2.0f / 9.0f, 0.5f * ccur);
        float x23 = fmaf(fmaf(i23, 2.0f / 3.0f, bcur), 2.0f / 3.0f, acur);
        float xbl = acur + (bcur + (0.5f * ccur + dcur * (1.0f / 3.0f)));

        // REAL prefetch: issue next-segment loads now; first use is stage 3
        // (anx) and the next iteration's top (b/c/d), so stages 0-2 of compute
        // (~3000 cyc) cover even a full HBM miss (~900 cyc).
        const int tn  = (t + 1 < SEGS) ? (t + 1) : (SEGS - 1);
        const int off = tn * CIN + ch;
        float anx = a_ptr[off];
        float bnx = bp[off];
        float cnx = cp[off];
        float dnx = dp[off];

        // ---- RK4 3/8-rule, dt = 1 ----
        MM_STAGE(z, x0, k1);
        float ys1 = fmaf(k1, 1.0f / 3.0f, z);
        MM_STAGE(ys1, x13, k2);
        float ys2 = z + (k2 - k1 * (1.0f / 3.0f));
        MM_STAGE(ys2, x23, k3);
        float xb  = (t < SEGS - 1) ? anx : xbl;   // vmcnt wait lands here
        float ys3 = z + (k1 - k2 + k3);
        MM_STAGE(ys3, xb, k4);

        z += (k1 + 3.0f * (k2 + k3) + k4) * 0.125f;
        acur = anx; bcur = bnx; ccur = cnx; dcur = dnx;
    }

    // ---- out[b] = z_fi @ W_out + b_out ----
    if (lane < 10) {
        float acc = b_out[lane];
#pragma unroll
        for (int m = 0; m < 64; ++m)
            acc = fmaf(rl(z, m), W_out[m * 10 + lane], acc);
        out[b * 10 + lane] = acc;
    }
}

extern "C" void kernel_launch(void* const* d_in, const int* in_sizes, int n_in,
                              void* d_out, int out_size, void* d_ws, size_t ws_size,
                              hipStream_t stream) {
    const float* cA     = (const float*)d_in[1];
    const float* cBc    = (const float*)d_in[2];
    const float* cCc    = (const float*)d_in[3];
    const float* cDc    = (const float*)d_in[4];
    const int*   fidx   = (const int*)d_in[5];
    const float* W_init = (const float*)d_in[6];
    const float* b_init = (const float*)d_in[7];
    const float* W1     = (const float*)d_in[8];
    const float* b1     = (const float*)d_in[9];
    const float* W2     = (const float*)d_in[10];
    const float* b2     = (const float*)d_in[11];
    const float* W_out  = (const float*)d_in[12];
    const float* b_out  = (const float*)d_in[13];

    node_kernel<<<dim3(NSEQ), dim3(64), 0, stream>>>(
        cA, cBc, cCc, cDc, fidx, W_init, b_init, W1, b1, W2, b2, W_out, b_out,
        (float*)d_out);
}

// Round 5
// 1691.793 us; speedup vs baseline: 6.2847x; 6.2847x over previous
//
#include <hip/hip_runtime.h>
#include <hip/hip_bf16.h>

#define NSEQ 512
#define SEGS 511     // L-1
#define CIN  32

typedef float v4f __attribute__((ext_vector_type(4)));

__device__ __forceinline__ float rl(float v, int lane) {
    return __int_as_float(__builtin_amdgcn_readlane(__float_as_int(v), lane));
}

__device__ __forceinline__ float tanhf_fast(float x) {
    // tanh(x) = sign(x) * (1 - e) / (1 + e),  e = exp(-2|x|)  — no overflow path
    float ax = fabsf(x);
    float e = __expf(-2.0f * ax);
#if __has_builtin(__builtin_amdgcn_rcpf)
    float r = (1.0f - e) * __builtin_amdgcn_rcpf(1.0f + e);
#else
    float r = (1.0f - e) / (1.0f + e);
#endif
    return copysignf(r, x);
}

// Block = 2 sequences x 2 waves. Wave w of a sequence owns h-columns
// [64w, 64w+64): mm1 needs NO cross-wave reduction (column split); mm2 is
// K-split over the wave's own h half, with ONE LDS exchange + ONE barrier
// per RK stage (parity double-buffered).
// W1 lives in LDS as w1t4[iq][col][4] (iq = i/4) so each lane reads its
// 4 weights as one aligned ds_read_b128; 64 lanes read 1024 contiguous
// bytes -> conflict-free. W2 column lives in registers (64 floats/lane).
__global__ __launch_bounds__(256, 1) void node_kernel(
    const float* __restrict__ cA, const float* __restrict__ cB,
    const float* __restrict__ cC, const float* __restrict__ cD,
    const int*   __restrict__ final_index,
    const float* __restrict__ W_init, const float* __restrict__ b_init,
    const float* __restrict__ W1, const float* __restrict__ b1,
    const float* __restrict__ W2, const float* __restrict__ b2,
    const float* __restrict__ W_out, const float* __restrict__ b_out,
    float* __restrict__ out)
{
    __shared__ float w1t4[24 * 128 * 4];      // 48 KiB: [iq][col][e] = W1[4iq+e][col]
    __shared__ float zx[2][2][2][64];         // [seq][parity][wave][lane]

    const int tid  = threadIdx.x;
    const int lane = tid & 63;
    const int wid  = tid >> 6;      // 0..3
    const int sq   = wid >> 1;      // sequence slot in block
    const int w    = wid & 1;       // column half
    const int b    = blockIdx.x * 2 + sq;
    const int ch   = lane & 31;
    const int col  = 64 * w + lane; // this lane's h column

    // ---- stage W1 into LDS (coalesced global reads, one-time) ----
    for (int idx = tid; idx < 96 * 128; idx += 256) {
        const int i = idx >> 7, c = idx & 127;
        w1t4[(((i >> 2) << 7) + c) * 4 + (i & 3)] = W1[idx];
    }

    // ---- W2 column in registers: w2c[j] = W2[64w+j][lane] ----
    float w2c[64];
#pragma unroll
    for (int j = 0; j < 64; ++j) w2c[j] = W2[(64 * w + j) * 64 + lane];
    const float b1c = b1[col];
    const float b2m = b2[lane];

    const float* a_ptr = cA + (size_t)b * SEGS * CIN;
    const float* bp    = cB + (size_t)b * SEGS * CIN;
    const float* cp    = cC + (size_t)b * SEGS * CIN;
    const float* dp    = cD + (size_t)b * SEGS * CIN;

    // ---- z0 = X(0) @ W_init + b_init ----
    float z = b_init[lane];
    {
        float a0 = a_ptr[ch];
#pragma unroll
        for (int i = 0; i < 32; ++i)
            z = fmaf(rl(a0, i), W_init[i * 64 + lane], z);
    }

    const int fi    = final_index[b];
    const int fio   = final_index[blockIdx.x * 2 + (sq ^ 1)];
    const int tmax  = fi > fio ? fi : fio;   // uniform loop bound per block

    float acur = a_ptr[ch], bcur = bp[ch], ccur = cp[ch], dcur = dp[ch];
    float k1 = 0.f, k2 = 0.f, k3 = 0.f, k4 = 0.f;

    __syncthreads();   // W1 staged

#define MM_STAGE(YS, XC, PAR, KOUT) do {                                   \
    float h0 = 0.f, h1 = 0.f;                                              \
    _Pragma("unroll")                                                      \
    for (int iq = 0; iq < 16; ++iq) {                                      \
        v4f wv = *reinterpret_cast<const v4f*>(&w1t4[(iq * 128 + col) * 4]); \
        float u0 = rl((YS), 4 * iq),     u1 = rl((YS), 4 * iq + 1);        \
        float u2 = rl((YS), 4 * iq + 2), u3 = rl((YS), 4 * iq + 3);        \
        h0 = fmaf(u0, wv.x, h0); h1 = fmaf(u1, wv.y, h1);                  \
        h0 = fmaf(u2, wv.z, h0); h1 = fmaf(u3, wv.w, h1);                  \
    }                                                                      \
    _Pragma("unroll")                                                      \
    for (int iq = 16; iq < 24; ++iq) {                                     \
        v4f wv = *reinterpret_cast<const v4f*>(&w1t4[(iq * 128 + col) * 4]); \
        const int ib = 4 * (iq - 16);                                      \
        float u0 = rl((XC), ib),     u1 = rl((XC), ib + 1);                \
        float u2 = rl((XC), ib + 2), u3 = rl((XC), ib + 3);                \
        h0 = fmaf(u0, wv.x, h0); h1 = fmaf(u1, wv.y, h1);                  \
        h0 = fmaf(u2, wv.z, h0); h1 = fmaf(u3, wv.w, h1);                  \
    }                                                                      \
    float h = tanhf_fast(h0 + h1 + b1c);                                   \
    float zp = 0.f, zq = 0.f;                                              \
    _Pragma("unroll")                                                      \
    for (int j = 0; j < 64; j += 2) {                                      \
        zp = fmaf(rl(h, j),     w2c[j],     zp);                           \
        zq = fmaf(rl(h, j + 1), w2c[j + 1], zq);                           \
    }                                                                      \
    zx[sq][PAR][w][lane] = zp + zq;                                        \
    __syncthreads();                                                       \
    float zo = zx[sq][PAR][w ^ 1][lane];                                   \
    KOUT = tanhf_fast(zp + zq + zo + b2m);                                 \
} while (0)

    for (int t = 0; t < tmax; ++t) {
        // spline points of this step from current-segment coeffs
        float x0  = acur;
        float i13 = fmaf(dcur, 1.0f / 9.0f, 0.5f * ccur);
        float x13 = fmaf(fmaf(i13, 1.0f / 3.0f, bcur), 1.0f / 3.0f, acur);
        float i23 = fmaf(dcur, 2.0f / 9.0f, 0.5f * ccur);
        float x23 = fmaf(fmaf(i23, 2.0f / 3.0f, bcur), 2.0f / 3.0f, acur);
        float xbl = acur + (bcur + (0.5f * ccur + dcur * (1.0f / 3.0f)));

        // real prefetch of next segment (first use: stage 3 / next iter top)
        const int tn  = (t + 1 < SEGS) ? (t + 1) : (SEGS - 1);
        const int off = tn * CIN + ch;
        float anx = a_ptr[off];
        float bnx = bp[off];
        float cnx = cp[off];
        float dnx = dp[off];

        MM_STAGE(z, x0, 0, k1);
        float ys1 = fmaf(k1, 1.0f / 3.0f, z);
        MM_STAGE(ys1, x13, 1, k2);
        float ys2 = z + (k2 - k1 * (1.0f / 3.0f));
        MM_STAGE(ys2, x23, 0, k3);
        float xb  = (t < SEGS - 1) ? anx : xbl;
        float ys3 = z + (k1 - k2 + k3);
        MM_STAGE(ys3, xb, 1, k4);

        float znew = z + (k1 + 3.0f * (k2 + k3) + k4) * 0.125f;
        z = (t < fi) ? znew : z;     // freeze state past this seq's final time
        acur = anx; bcur = bnx; ccur = cnx; dcur = dnx;
    }

    // ---- out[b] = z_fi @ W_out + b_out  (wave 0 of each sequence) ----
    if (w == 0 && lane < 10) {
        float acc = b_out[lane];
#pragma unroll
        for (int m = 0; m < 64; ++m)
            acc = fmaf(rl(z, m), W_out[m * 10 + lane], acc);
        out[b * 10 + lane] = acc;
    }
}

extern "C" void kernel_launch(void* const* d_in, const int* in_sizes, int n_in,
                              void* d_out, int out_size, void* d_ws, size_t ws_size,
                              hipStream_t stream) {
    const float* cA     = (const float*)d_in[1];
    const float* cBc    = (const float*)d_in[2];
    const float* cCc    = (const float*)d_in[3];
    const float* cDc    = (const float*)d_in[4];
    const int*   fidx   = (const int*)d_in[5];
    const float* W_init = (const float*)d_in[6];
    const float* b_init = (const float*)d_in[7];
    const float* W1     = (const float*)d_in[8];
    const float* b1     = (const float*)d_in[9];
    const float* W2     = (const float*)d_in[10];
    const float* b2     = (const float*)d_in[11];
    const float* W_out  = (const float*)d_in[12];
    const float* b_out  = (const float*)d_in[13];

    node_kernel<<<dim3(NSEQ / 2), dim3(256), 0, stream>>>(
        cA, cBc, cCc, cDc, fidx, W_init, b_init, W1, b1, W2, b2, W_out, b_out,
        (float*)d_out);
}